// Round 3
// baseline (599.935 us; speedup 1.0000x reference)
//
#include <hip/hip_runtime.h>
#include <hip/hip_bf16.h>

// PQLinear: C[8192,4096] = X[8192,4096] @ W[4096,4096]^T
//   W[o][k] = codebooks[k/128][assignments[o][k/128]][k%128]
// Strategy: gather W -> bf16 in ws, convert X -> bf16 in ws, then m97-style
// 128x128 bf16 MFMA GEMM (B^T layout, global_load_lds width=16 staging).
// ws usage: 4096*4096*2 + 8192*4096*2 = 100,663,296 bytes.

#define K_DIM 4096
#define N_DIM 4096
#define M_DIM 8192

typedef __attribute__((ext_vector_type(8))) __bf16 bf16x8;
typedef __attribute__((ext_vector_type(4))) float f32x4;
typedef __attribute__((ext_vector_type(8))) unsigned short ushort8;

__device__ __forceinline__ unsigned short f2bf_rne(float f) {
    unsigned u = __builtin_bit_cast(unsigned, f);
    u += 0x7fffu + ((u >> 16) & 1u);   // round-to-nearest-even (no NaN inputs)
    return (unsigned short)(u >> 16);
}

// ---------------------------------------------------------------------------
// Kernel 1: gather + convert W. One thread -> 8 consecutive k of one row o.
// grid = 4096*4096/8/256 = 8192 blocks.
__global__ void gather_w_kernel(const float* __restrict__ cb,
                                const int* __restrict__ asn,
                                unsigned short* __restrict__ Wb) {
    int gid = blockIdx.x * 256 + threadIdx.x;
    int o   = gid >> 9;              // 512 threads per output row
    int k   = (gid & 511) << 3;      // 8 elems, always within one subvector
    int s   = k >> 7;
    int c   = asn[(o << 5) + s];
    const float* src = cb + ((((s << 8) + c) << 7) + (k & 127));
    float4 v0 = *(const float4*)src;
    float4 v1 = *(const float4*)(src + 4);
    ushort8 r;
    r[0] = f2bf_rne(v0.x); r[1] = f2bf_rne(v0.y);
    r[2] = f2bf_rne(v0.z); r[3] = f2bf_rne(v0.w);
    r[4] = f2bf_rne(v1.x); r[5] = f2bf_rne(v1.y);
    r[6] = f2bf_rne(v1.z); r[7] = f2bf_rne(v1.w);
    *(ushort8*)(Wb + (size_t)o * K_DIM + k) = r;
}

// ---------------------------------------------------------------------------
// Kernel 2: convert X fp32 -> bf16. One thread -> 8 elems.
// grid = 8192*4096/8/256 = 16384 blocks.
__global__ void convert_x_kernel(const float* __restrict__ X,
                                 unsigned short* __restrict__ Xb) {
    size_t base = (size_t)(blockIdx.x * 256 + threadIdx.x) * 8;
    float4 v0 = *(const float4*)(X + base);
    float4 v1 = *(const float4*)(X + base + 4);
    ushort8 r;
    r[0] = f2bf_rne(v0.x); r[1] = f2bf_rne(v0.y);
    r[2] = f2bf_rne(v0.z); r[3] = f2bf_rne(v0.w);
    r[4] = f2bf_rne(v1.x); r[5] = f2bf_rne(v1.y);
    r[6] = f2bf_rne(v1.z); r[7] = f2bf_rne(v1.w);
    *(ushort8*)(Xb + base) = r;
}

// ---------------------------------------------------------------------------
// Kernel 3: m97-structure GEMM. C = A * B^T, A[M][K], B[N][K], both bf16.
// 128x128 tile, BK=32, 256 threads (4 waves, 2x2), 16x16x32 bf16 MFMA.
__global__ __launch_bounds__(256) void gemm_bt_kernel(
    const __bf16* __restrict__ A, const __bf16* __restrict__ B,
    float* __restrict__ C) {
    constexpr int K = K_DIM, N = N_DIM;
    __shared__ __bf16 As[128 * 32];   // 8 KB, linear (global_load_lds dest)
    __shared__ __bf16 Bs[128 * 32];   // 8 KB

    const int tid = threadIdx.x;
    const int w   = tid >> 6;         // wave 0..3
    const int l   = tid & 63;         // lane
    const int bid = blockIdx.x;       // 2048 blocks = 64 m-tiles x 32 n-tiles
    const long m0 = (long)(bid >> 5) * 128;
    const long n0 = (long)(bid & 31) * 128;
    const int wr  = w >> 1, wc = w & 1;   // wave -> 64x64 quadrant
    const int lr  = l & 15;               // fragment row/col within 16
    const int kh  = l >> 4;               // k-slot 0..3 (8 elems each)

    // staging: wave w loads rows [w*32, w*32+32) of each tile; 2 insts of
    // 1 KB (16 rows x 64B) each. lane: row += l>>2, byte col = (l&3)*16.
    const __bf16* gA = A + (m0 + w * 32 + (l >> 2)) * (long)K + ((l & 3) * 8);
    const __bf16* gB = B + (n0 + w * 32 + (l >> 2)) * (long)K + ((l & 3) * 8);
    __bf16* dA = &As[(w * 32) * 32];      // wave-uniform LDS base (+lane*16 HW)
    __bf16* dB = &Bs[(w * 32) * 32];

    f32x4 acc[4][4] = {};

    for (int k0 = 0; k0 < K; k0 += 32) {
        __builtin_amdgcn_global_load_lds(
            (const __attribute__((address_space(1))) void*)(gA + k0),
            (__attribute__((address_space(3))) void*)dA, 16, 0, 0);
        __builtin_amdgcn_global_load_lds(
            (const __attribute__((address_space(1))) void*)(gA + k0 + 16 * (long)K),
            (__attribute__((address_space(3))) void*)(dA + 16 * 32), 16, 0, 0);
        __builtin_amdgcn_global_load_lds(
            (const __attribute__((address_space(1))) void*)(gB + k0),
            (__attribute__((address_space(3))) void*)dB, 16, 0, 0);
        __builtin_amdgcn_global_load_lds(
            (const __attribute__((address_space(1))) void*)(gB + k0 + 16 * (long)K),
            (__attribute__((address_space(3))) void*)(dB + 16 * 32), 16, 0, 0);
        __syncthreads();   // compiler drains vmcnt(0) before s_barrier

        bf16x8 a[4], b[4];
        #pragma unroll
        for (int m = 0; m < 4; ++m)
            a[m] = *(const bf16x8*)&As[(wr * 64 + m * 16 + lr) * 32 + kh * 8];
        #pragma unroll
        for (int n = 0; n < 4; ++n)
            b[n] = *(const bf16x8*)&Bs[(wc * 64 + n * 16 + lr) * 32 + kh * 8];
        #pragma unroll
        for (int m = 0; m < 4; ++m)
            #pragma unroll
            for (int n = 0; n < 4; ++n)
                acc[m][n] = __builtin_amdgcn_mfma_f32_16x16x32_bf16(
                    a[m], b[n], acc[m][n], 0, 0, 0);
        __syncthreads();   // protect LDS before next stage overwrites
    }

    // C/D layout (m89-verified): col = lane&15, row = (lane>>4)*4 + reg
    const int crow = kh * 4;
    #pragma unroll
    for (int m = 0; m < 4; ++m)
        #pragma unroll
        for (int n = 0; n < 4; ++n) {
            float* cp = C + (m0 + wr * 64 + m * 16 + crow) * (long)N
                          + n0 + wc * 64 + n * 16 + lr;
            #pragma unroll
            for (int j = 0; j < 4; ++j) cp[(long)j * N] = acc[m][n][j];
        }
}

// ---------------------------------------------------------------------------
extern "C" void kernel_launch(void* const* d_in, const int* in_sizes, int n_in,
                              void* d_out, int out_size, void* d_ws, size_t ws_size,
                              hipStream_t stream) {
    const float* x   = (const float*)d_in[0];   // [4,2048,4096] fp32
    const float* cb  = (const float*)d_in[1];   // [32,256,128] fp32
    const int*   asn = (const int*)d_in[2];     // [4096,32] int32
    float* out = (float*)d_out;                 // [4,2048,4096] fp32

    unsigned short* Wb = (unsigned short*)d_ws;                   // 33.5 MB
    unsigned short* Xb = Wb + (size_t)N_DIM * K_DIM;              // 67 MB

    gather_w_kernel<<<8192, 256, 0, stream>>>(cb, asn, Wb);
    convert_x_kernel<<<16384, 256, 0, stream>>>(x, Xb);
    gemm_bt_kernel<<<2048, 256, 0, stream>>>(
        (const __bf16*)Xb, (const __bf16*)Wb, out);
}

// Round 5
// 461.202 us; speedup vs baseline: 1.3008x; 1.3008x over previous
//
#include <hip/hip_runtime.h>
#include <hip/hip_bf16.h>

// PQLinear: C[8192,4096] = X[8192,4096] @ W[4096,4096]^T
//   W[o][k] = codebooks[k/128][assignments[o][k/128]][k%128]
// R4: 256x256 tile, BK=32, 8 waves (2Mx4N), 4-slot LDS pipeline (128 KiB),
// depth-3 prefetch with counted s_waitcnt vmcnt(8) (never 0 in main loop),
// ONE raw s_barrier per K-tile (~32 MFMA/barrier, AITER-shaped), setprio
// around MFMA cluster, XOR-swizzled LDS (pre-swizzled global source +
// swizzled ds_read; linear gload_lds dest), bijective XCD blockIdx swizzle.

#define K_DIM 4096
#define N_DIM 4096
#define M_DIM 8192

typedef __attribute__((ext_vector_type(8))) __bf16 bf16x8;
typedef __attribute__((ext_vector_type(4))) float f32x4;
typedef __attribute__((ext_vector_type(8))) unsigned short ushort8;

__device__ __forceinline__ unsigned short f2bf_rne(float f) {
    unsigned u = __builtin_bit_cast(unsigned, f);
    u += 0x7fffu + ((u >> 16) & 1u);   // RNE (inputs are finite randn)
    return (unsigned short)(u >> 16);
}

// ---------------------------------------------------------------------------
// Kernel 1: gather + convert W -> bf16. grid-stride, 2048 blocks.
__global__ void gather_w_kernel(const float* __restrict__ cb,
                                const int* __restrict__ asn,
                                unsigned short* __restrict__ Wb) {
    for (int gid = blockIdx.x * 256 + threadIdx.x; gid < (N_DIM << 9);
         gid += 2048 * 256) {
        int o = gid >> 9;                // 512 threads per output row
        int k = (gid & 511) << 3;        // 8 elems, within one subvector
        int s = k >> 7;
        int c = asn[(o << 5) + s];
        const float* src = cb + ((((s << 8) + c) << 7) + (k & 127));
        float4 v0 = *(const float4*)src;
        float4 v1 = *(const float4*)(src + 4);
        ushort8 r;
        r[0] = f2bf_rne(v0.x); r[1] = f2bf_rne(v0.y);
        r[2] = f2bf_rne(v0.z); r[3] = f2bf_rne(v0.w);
        r[4] = f2bf_rne(v1.x); r[5] = f2bf_rne(v1.y);
        r[6] = f2bf_rne(v1.z); r[7] = f2bf_rne(v1.w);
        *(ushort8*)(Wb + (size_t)o * K_DIM + k) = r;
    }
}

// ---------------------------------------------------------------------------
// Kernel 2: convert X fp32 -> bf16. grid-stride, 2048 blocks.
__global__ void convert_x_kernel(const float* __restrict__ X,
                                 unsigned short* __restrict__ Xb) {
    for (size_t i = blockIdx.x * 256 + threadIdx.x;
         i < (size_t)M_DIM * K_DIM / 8; i += 2048 * 256) {
        size_t base = i * 8;
        float4 v0 = *(const float4*)(X + base);
        float4 v1 = *(const float4*)(X + base + 4);
        ushort8 r;
        r[0] = f2bf_rne(v0.x); r[1] = f2bf_rne(v0.y);
        r[2] = f2bf_rne(v0.z); r[3] = f2bf_rne(v0.w);
        r[4] = f2bf_rne(v1.x); r[5] = f2bf_rne(v1.y);
        r[6] = f2bf_rne(v1.z); r[7] = f2bf_rne(v1.w);
        *(ushort8*)(Xb + base) = r;
    }
}

// ---------------------------------------------------------------------------
// Kernel 3: pipelined GEMM. C = A * B^T, A[M][K], B[N][K] bf16, C fp32.
// 512 threads = 8 waves; wave (wr,wc) owns 128x64 of the 256x256 tile.
// LDS: 4 slots x (A[256][32] + B[256][32]) bf16 = 4 x 32 KiB = 128 KiB.
// Swizzle: logical (row r, 16B-slot kh) stored at phys slot kh ^ ((r>>1)&3).
#define T_TILES 128          // K / BK = 4096 / 32
#define SLOT_E  16384        // elements per slot (A 8192 + B 8192)

__global__ __launch_bounds__(512, 2) void gemm_pipe_kernel(
    const __bf16* __restrict__ A, const __bf16* __restrict__ B,
    float* __restrict__ C) {
    constexpr int K = K_DIM, N = N_DIM;
    extern __shared__ __bf16 lds[];      // 65536 elems = 128 KiB

    const int tid = threadIdx.x;
    const int w   = tid >> 6;            // wave 0..7
    const int l   = tid & 63;
    const int wr  = w >> 2;              // 0..1: A-rows [wr*128, +128)
    const int wc  = w & 3;               // 0..3: B-rows [wc*64, +64)
    const int lr  = l & 15;
    const int khr = l >> 4;              // k-slot 0..3 for frag reads

    // XCD-aware bijective swizzle: nwg = 512 = 64 per XCD (512 % 8 == 0).
    const int bid = blockIdx.x;
    const int swz = (bid & 7) * 64 + (bid >> 3);
    const long m0 = (long)(swz >> 4) * 256;   // 32 m-tiles
    const long n0 = (long)(swz & 15) * 256;   // 16 n-tiles

    // --- staging sources (pre-swizzled global column) -----------------------
    // gload_lds i covers rows w*32+i*16 .. +16; lane l -> row += l>>2,
    // phys 16B-slot l&3. Source col slot = (l&3) ^ swz(row), swz(row)=(l>>3)&3.
    const int scol = (((l & 3) ^ ((l >> 3) & 3)) << 3);    // elems
    const int srow = w * 32 + (l >> 2);
    const __bf16* gA0 = A + (m0 + srow) * (long)K + scol;
    const __bf16* gA1 = gA0 + 16 * (long)K;
    const __bf16* gB0 = B + (n0 + srow) * (long)K + scol;
    const __bf16* gB1 = gB0 + 16 * (long)K;

    // --- fragment read offsets (swizzled) -----------------------------------
    const int sw    = (lr >> 1) & 3;
    const int aoff0 = (wr * 128 + lr) * 32 + ((khr ^ sw) << 3);
    const int boff0 = 8192 + (wc * 64 + lr) * 32 + ((khr ^ sw) << 3);

    f32x4 acc[8][4] = {};

    // one gload_lds = 64 lanes x 16B = 16 rows x 64B (one row = BK=32 bf16)
    #define STAGE(t) do {                                                     \
        const int s_ = (t) & 3;                                               \
        __bf16* b_ = lds + s_ * SLOT_E;                                       \
        const int ko_ = (t) * 32;                                             \
        __builtin_amdgcn_global_load_lds(                                     \
            (const __attribute__((address_space(1))) void*)(gA0 + ko_),       \
            (__attribute__((address_space(3))) void*)(b_ + (w * 32) * 32),    \
            16, 0, 0);                                                        \
        __builtin_amdgcn_global_load_lds(                                     \
            (const __attribute__((address_space(1))) void*)(gA1 + ko_),       \
            (__attribute__((address_space(3))) void*)(b_ + (w * 32 + 16) * 32),\
            16, 0, 0);                                                        \
        __builtin_amdgcn_global_load_lds(                                     \
            (const __attribute__((address_space(1))) void*)(gB0 + ko_),       \
            (__attribute__((address_space(3))) void*)(b_ + 8192 + (w * 32) * 32),\
            16, 0, 0);                                                        \
        __builtin_amdgcn_global_load_lds(                                     \
            (const __attribute__((address_space(1))) void*)(gB1 + ko_),       \
            (__attribute__((address_space(3))) void*)(b_ + 8192 + (w * 32 + 16) * 32),\
            16, 0, 0);                                                        \
    } while (0)

    #define COMPUTE(t) do {                                                   \
        const __bf16* pa_ = lds + ((t) & 3) * SLOT_E + aoff0;                 \
        const __bf16* pb_ = lds + ((t) & 3) * SLOT_E + boff0;                 \
        bf16x8 af_[8], bf_[4];                                                \
        _Pragma("unroll")                                                     \
        for (int m = 0; m < 8; ++m) af_[m] = *(const bf16x8*)(pa_ + m * 512); \
        _Pragma("unroll")                                                     \
        for (int n = 0; n < 4; ++n) bf_[n] = *(const bf16x8*)(pb_ + n * 512); \
        __builtin_amdgcn_s_setprio(1);                                        \
        _Pragma("unroll")                                                     \
        for (int m = 0; m < 8; ++m)                                           \
            _Pragma("unroll")                                                 \
            for (int n = 0; n < 4; ++n)                                       \
                acc[m][n] = __builtin_amdgcn_mfma_f32_16x16x32_bf16(          \
                    af_[m], bf_[n], acc[m][n], 0, 0, 0);                      \
        __builtin_amdgcn_s_setprio(0);                                        \
    } while (0)

    // prologue: fill slots 0..2 (12 loads/thread in flight)
    STAGE(0); STAGE(1); STAGE(2);

    // main loop: counted vmcnt — own tile-t loads (oldest 4) landed; barrier
    // collectivizes; then overwrite slot (t+3)&3 = (t-1)&3, whose reads all
    // completed before barrier(t).  vmcnt never drains to 0 here (T4).
    for (int t = 0; t < T_TILES - 3; ++t) {
        asm volatile("s_waitcnt vmcnt(8)" ::: "memory");
        __builtin_amdgcn_s_barrier();
        STAGE(t + 3);
        COMPUTE(t);
    }
    // epilogue: drain 8 -> 4 -> 0
    asm volatile("s_waitcnt vmcnt(8)" ::: "memory");
    __builtin_amdgcn_s_barrier();
    COMPUTE(T_TILES - 3);
    asm volatile("s_waitcnt vmcnt(4)" ::: "memory");
    __builtin_amdgcn_s_barrier();
    COMPUTE(T_TILES - 2);
    asm volatile("s_waitcnt vmcnt(0)" ::: "memory");
    __builtin_amdgcn_s_barrier();
    COMPUTE(T_TILES - 1);

    // C/D layout (m89-verified): col = lane&15, row = (lane>>4)*4 + reg
    const int crow = khr * 4;
    #pragma unroll
    for (int m = 0; m < 8; ++m)
        #pragma unroll
        for (int n = 0; n < 4; ++n) {
            float* cp = C + (m0 + wr * 128 + m * 16 + crow) * (long)N
                          + n0 + wc * 64 + n * 16 + lr;
            #pragma unroll
            for (int j = 0; j < 4; ++j) cp[(long)j * N] = acc[m][n][j];
        }
    #undef STAGE
    #undef COMPUTE
}

// ---------------------------------------------------------------------------
extern "C" void kernel_launch(void* const* d_in, const int* in_sizes, int n_in,
                              void* d_out, int out_size, void* d_ws, size_t ws_size,
                              hipStream_t stream) {
    const float* x   = (const float*)d_in[0];   // [4,2048,4096] fp32
    const float* cb  = (const float*)d_in[1];   // [32,256,128] fp32
    const int*   asn = (const int*)d_in[2];     // [4096,32] int32
    float* out = (float*)d_out;                 // [4,2048,4096] fp32

    unsigned short* Wb = (unsigned short*)d_ws;                   // 33.5 MB
    unsigned short* Xb = Wb + (size_t)N_DIM * K_DIM;              // 67 MB

    gather_w_kernel<<<2048, 256, 0, stream>>>(cb, asn, Wb);
    convert_x_kernel<<<2048, 256, 0, stream>>>(x, Xb);
    // 512 blocks = 32 m-tiles x 16 n-tiles; 128 KiB dynamic LDS
    gemm_pipe_kernel<<<512, 512, 131072, stream>>>(
        (const __bf16*)Xb, (const __bf16*)Wb, out);
}